// Round 2
// baseline (211.426 us; speedup 1.0000x reference)
//
#include <hip/hip_runtime.h>
#include <math.h>

#define NB 16
#define NL 1024
#define NH 8
#define NE 64
#define NWIN 1024
#define NG 64

#define SCH 128     // s-chunk per block in k_attn_out
#define SROW 136    // sb row stride in shorts (16B-aligned: 136*2=272 ≡ 0 mod 16)

typedef __attribute__((ext_vector_type(8))) short short8;
typedef __attribute__((ext_vector_type(4))) float floatx4;

__device__ __forceinline__ short f2bf(float x) {
    unsigned u = __float_as_uint(x);
    u += 0x7fffu + ((u >> 16) & 1u);   // round-to-nearest-even
    return (short)(u >> 16);
}
__device__ __forceinline__ float dot4(float4 a, float4 b) {
    return fmaf(a.x, b.x, fmaf(a.y, b.y, fmaf(a.z, b.z, a.w * b.w)));
}

// Raw barrier: orders LDS traffic (lgkmcnt) but does NOT drain vmcnt —
// keeps the async global_load_lds v-staging in flight across phases.
__device__ __forceinline__ void lgkm_barrier() {
    asm volatile("s_waitcnt lgkmcnt(0)" ::: "memory");
    __builtin_amdgcn_s_barrier();
}

// 16B-per-lane async global->LDS (dest = wave-uniform base + lane*16B).
__device__ __forceinline__ void gl_lds16(const float* g, float* l) {
    __builtin_amdgcn_global_load_lds(
        (const __attribute__((address_space(1))) float*)g,
        (__attribute__((address_space(3))) float*)l, 16, 0, 0);
}

// Fused kernel: tanh-MLP (t stays in LDS) + qp/qn reduction.
// v5 (unchanged this round): one row per 16-lane group, 1024 blocks.
__global__ __launch_bounds__(256, 4) void k_sel_q(
    const float* __restrict__ x, const float* __restrict__ mlp_w,
    const float* __restrict__ mlp_b, const float* __restrict__ q,
    float* __restrict__ qp, float* __restrict__ qn)
{
    __shared__ float4 w_lds[8][NWIN / 4];   // 32 KB
    __shared__ float t_lds[128];
    __shared__ float redp[4][64], redn[4][64];

    int tid = threadIdx.x;
    int blk = blockIdx.x;
    int ee = blk & 7, bh = blk >> 3;
    int b = bh >> 3, h = bh & 7;
    int w = tid >> 6, lane = tid & 63;
    int sq = lane >> 4, c = lane & 15;

    const float4* w4 = (const float4*)mlp_w;
    float4* wl = (float4*)w_lds;
    #pragma unroll
    for (int i = 0; i < 8; ++i)
        wl[tid + 256 * i] = w4[tid + 256 * i];
    __syncthreads();

    // ---- phase 1: tanh-MLP, one row per 16-lane group (16 rows/block) ----
    int row_loc = w * 4 + sq;                               // [0,16)
    int r = b * 1024 + h * 128 + ee * 16 + row_loc;
    const float4* xr = (const float4*)(x + (size_t)r * NWIN);
    float4 a03 = make_float4(0,0,0,0), a47 = make_float4(0,0,0,0);
    #pragma unroll
    for (int i = 0; i < 16; ++i) {
        float4 xv = xr[i * 16 + c];
        a03.x += dot4(xv, w_lds[0][i * 16 + c]);
        a03.y += dot4(xv, w_lds[1][i * 16 + c]);
        a03.z += dot4(xv, w_lds[2][i * 16 + c]);
        a03.w += dot4(xv, w_lds[3][i * 16 + c]);
        a47.x += dot4(xv, w_lds[4][i * 16 + c]);
        a47.y += dot4(xv, w_lds[5][i * 16 + c]);
        a47.z += dot4(xv, w_lds[6][i * 16 + c]);
        a47.w += dot4(xv, w_lds[7][i * 16 + c]);
    }
    // 4-level butterfly within the 16-lane group
    #pragma unroll
    for (int off = 1; off < 16; off <<= 1) {
        a03.x += __shfl_xor(a03.x, off, 64);
        a03.y += __shfl_xor(a03.y, off, 64);
        a03.z += __shfl_xor(a03.z, off, 64);
        a03.w += __shfl_xor(a03.w, off, 64);
        a47.x += __shfl_xor(a47.x, off, 64);
        a47.y += __shfl_xor(a47.y, off, 64);
        a47.z += __shfl_xor(a47.z, off, 64);
        a47.w += __shfl_xor(a47.w, off, 64);
    }
    if (c == 0) {
        float4 b03 = *(const float4*)mlp_b;
        float4 b47 = *(const float4*)(mlp_b + 4);
        float4 t03, t47;
        t03.x = tanhf(a03.x + b03.x); t03.y = tanhf(a03.y + b03.y);
        t03.z = tanhf(a03.z + b03.z); t03.w = tanhf(a03.w + b03.w);
        t47.x = tanhf(a47.x + b47.x); t47.y = tanhf(a47.y + b47.y);
        t47.z = tanhf(a47.z + b47.z); t47.w = tanhf(a47.w + b47.w);
        *(float4*)&t_lds[row_loc * 8]     = t03;
        *(float4*)&t_lds[row_loc * 8 + 4] = t47;
    }
    __syncthreads();

    // ---- phase 2: qp/qn partial over l in [ee*128, ee*128+128) ----
    int lo = sq, e4 = c;
    float4 accp = make_float4(0,0,0,0), accn = make_float4(0,0,0,0);
    #pragma unroll
    for (int i = 0; i < 8; ++i) {
        int l_loc = w * 32 + i * 4 + lo;
        float tv = t_lds[l_loc];
        int l = ee * 128 + l_loc;
        float4 qv = *(const float4*)(q + (((size_t)(b * NL + l)) * NH + h) * NE + e4 * 4);
        float tp = fmaxf(tv, 0.f), tn = fminf(tv, 0.f);
        accp.x = fmaf(tp, qv.x, accp.x); accp.y = fmaf(tp, qv.y, accp.y);
        accp.z = fmaf(tp, qv.z, accp.z); accp.w = fmaf(tp, qv.w, accp.w);
        accn.x = fmaf(tn, qv.x, accn.x); accn.y = fmaf(tn, qv.y, accn.y);
        accn.z = fmaf(tn, qv.z, accn.z); accn.w = fmaf(tn, qv.w, accn.w);
    }
    #pragma unroll
    for (int off = 16; off <= 32; off <<= 1) {
        accp.x += __shfl_xor(accp.x, off, 64); accp.y += __shfl_xor(accp.y, off, 64);
        accp.z += __shfl_xor(accp.z, off, 64); accp.w += __shfl_xor(accp.w, off, 64);
        accn.x += __shfl_xor(accn.x, off, 64); accn.y += __shfl_xor(accn.y, off, 64);
        accn.z += __shfl_xor(accn.z, off, 64); accn.w += __shfl_xor(accn.w, off, 64);
    }
    if (lo == 0) {
        *(float4*)&redp[w][e4 * 4] = accp;
        *(float4*)&redn[w][e4 * 4] = accn;
    }
    __syncthreads();
    if (tid < 64) {
        atomicAdd(&qp[bh * NE + tid], redp[0][tid] + redp[1][tid] + redp[2][tid] + redp[3][tid]);
    } else if (tid < 128) {
        int e = tid - 64;
        atomicAdd(&qn[bh * NE + e], redn[0][e] + redn[1][e] + redn[2][e] + redn[3][e]);
    }
}

// Attention kernel v5: per (b, h, s-chunk of 128).
// v-tile (128 s x 16 e per wave) is staged global->LDS asynchronously at
// kernel entry (8x global_load_lds dwordx4 per wave) and stays in flight
// across phases A/B (raw lgkm-only barriers). Phase C reads it from LDS
// with a row-slot involution (slot = s ^ bit3(s)) applied identically on
// the staging source and the read side -> 2-way (free) bank access.
__global__ __launch_bounds__(256, 4) void k_attn_out(
    const float* __restrict__ keys, const float* __restrict__ values,
    const float* __restrict__ sel_W,
    const float* __restrict__ qp, const float* __restrict__ qn,
    float* __restrict__ out)
{
    __shared__ short sb[NG][SROW];          // 17408 B  series bf16, [g][s]
    __shared__ float vst[4][2048];          // 32768 B  per-wave v tile [slot][e]
    __shared__ float ap_l[SCH], an_l[SCH];  // 1024 B
    __shared__ float2 wpn[NG];              // 512 B
    __shared__ float mxdn[2][SCH];          // 1024 B (mx then dn, aliased)

    int tid = threadIdx.x, blk = blockIdx.x;
    int chunk = blk & 7, bh = blk >> 3;
    int b = bh >> 3, h = bh & 7;
    int w = tid >> 6, lane = tid & 63;
    int c = lane & 15, sq = lane >> 4;
    const float scale = 0.125f;             // 1/sqrt(64)
    int s0 = chunk * SCH;

    // ---- async v-staging (issued before everything else) ----
    // inst i, lane: dest slot_row = 16i + (lane>>2), e4 = lane&3.
    // source s_loc = (lane>>2) ^ bit3(slot_row) = (lane>>2) ^ ((lane>>5)&1).
    {
        float* vstW = &vst[w][0];
        int s_loc = (lane >> 2) ^ ((lane >> 5) & 1);
        const float* vsrc = values + (((size_t)(b * NL + s0 + s_loc)) * NH + h) * NE
                          + 16 * w + 4 * (lane & 3);
        #pragma unroll
        for (int i = 0; i < 8; ++i)
            gl_lds16(vsrc + (size_t)(16 * i) * (NH * NE), vstW + 256 * i);
    }

    if (tid < NG) {
        float W = sel_W[h * NG + tid];
        wpn[tid] = make_float2(fmaxf(W, 0.f) * scale, fminf(W, 0.f) * scale);
    }

    const float4 qp4 = *(const float4*)(qp + bh * NE + c * 4);
    const float4 qn4 = *(const float4*)(qn + bh * NE + c * 4);

    // ---- phase A: ap/an (wave owns 32 s) ----
    #pragma unroll
    for (int p = 0; p < 8; ++p) {
        int sl = w * 32 + p * 4 + sq;
        float4 kv = *(const float4*)(keys + (((size_t)(b * NL + s0 + sl)) * NH + h) * NE + c * 4);
        float pp = dot4(kv, qp4);
        float pn = dot4(kv, qn4);
        #pragma unroll
        for (int m_ = 1; m_ <= 8; m_ <<= 1) {
            pp += __shfl_xor(pp, m_, 64);
            pn += __shfl_xor(pn, m_, 64);
        }
        if (c == 0) { ap_l[sl] = pp; an_l[sl] = pn; }
    }
    lgkm_barrier();

    // ---- phase B: softmax over g, split g-range across thread halves ----
    {
        int s_ = tid & 127, gh = tid >> 7, g0 = gh * 32;
        float ap = ap_l[s_], an = an_l[s_];
        float m = -1e30f;
        #pragma unroll 8
        for (int g = 0; g < 32; ++g) {
            float2 wv = wpn[g0 + g];
            m = fmaxf(m, fmaf(wv.x, ap, wv.y * an));
        }
        mxdn[gh][s_] = m;
        lgkm_barrier();
        m = fmaxf(mxdn[0][s_], mxdn[1][s_]);
        lgkm_barrier();                      // WAR: protect mx before dn overwrite
        float d = 0.f;
        #pragma unroll 8
        for (int g = 0; g < 32; ++g) {
            float2 wv = wpn[g0 + g];
            d += __expf(fmaf(wv.x, ap, wv.y * an) - m);
        }
        mxdn[gh][s_] = d;
        lgkm_barrier();
        float inv = 1.0f / (mxdn[0][s_] + mxdn[1][s_]);
        #pragma unroll 8
        for (int g = 0; g < 32; ++g) {
            float2 wv = wpn[g0 + g];
            sb[g0 + g][s_] = f2bf(__expf(fmaf(wv.x, ap, wv.y * an) - m) * inv);
        }
    }
    lgkm_barrier();

    // wait for the wave-local staged v tile (no cross-wave sharing -> no barrier)
    asm volatile("s_waitcnt vmcnt(0)" ::: "memory");
    __builtin_amdgcn_sched_barrier(0);

    // ---- phase C: MFMA, wave owns e-tile [16w, 16w+16) ----
    floatx4 acc[4] = {{0.f,0.f,0.f,0.f},{0.f,0.f,0.f,0.f},
                      {0.f,0.f,0.f,0.f},{0.f,0.f,0.f,0.f}};
    const float* vstW = &vst[w][0];
    int sq1 = sq & 1;                       // bit3 of row for j<8, any ks
    #pragma unroll
    for (int ks = 0; ks < 4; ++ks) {
        short8 av;
        #pragma unroll
        for (int j = 0; j < 8; ++j) {
            int slot = (ks * 32 + sq * 8 + j) ^ sq1;
            av[j] = f2bf(vstW[slot * 16 + c]);
        }
        #pragma unroll
        for (int n = 0; n < 4; ++n) {
            short8 bv = *(const short8*)&sb[16 * n + c][ks * 32 + sq * 8];
            acc[n] = __builtin_amdgcn_mfma_f32_16x16x32_bf16(av, bv, acc[n], 0, 0, 0);
        }
    }

    // epilogue: D[row=sq*4+r][col=c]; 8 s-chunk blocks accumulate per (b,h).
    #pragma unroll
    for (int n = 0; n < 4; ++n) {
        #pragma unroll
        for (int r = 0; r < 4; ++r) {
            int e = 16 * w + sq * 4 + r;
            int g = 16 * n + c;
            atomicAdd(&out[((size_t)(b * NE + e) * NH + h) * NG + g], acc[n][r]);
        }
    }
}

extern "C" void kernel_launch(void* const* d_in, const int* in_sizes, int n_in,
                              void* d_out, int out_size, void* d_ws, size_t ws_size,
                              hipStream_t stream) {
    (void)in_sizes; (void)n_in; (void)ws_size;
    const float* queries = (const float*)d_in[0];
    const float* keys    = (const float*)d_in[1];
    const float* values  = (const float*)d_in[2];
    const float* x       = (const float*)d_in[3];
    const float* mlp_w   = (const float*)d_in[4];
    const float* mlp_b   = (const float*)d_in[5];
    const float* sel_W   = (const float*)d_in[6];
    float* out = (float*)d_out;

    // ws layout (floats): qp[8192] | qn[8192]
    float* qp_ws = (float*)d_ws;
    float* qn_ws = qp_ws + NB * NH * NE;

    hipMemsetAsync(out, 0, (size_t)out_size * sizeof(float), stream);
    hipMemsetAsync(qp_ws, 0, (size_t)2 * NB * NH * NE * sizeof(float), stream);

    k_sel_q<<<dim3(NB * NH * 8), dim3(256), 0, stream>>>(x, mlp_w, mlp_b,
                                                          queries, qp_ws, qn_ws);
    k_attn_out<<<dim3(NB * NH * 8), dim3(256), 0, stream>>>(keys, values, sel_W,
                                                            qp_ws, qn_ws, out);
}

// Round 3
// 198.899 us; speedup vs baseline: 1.0630x; 1.0630x over previous
//
#include <hip/hip_runtime.h>
#include <math.h>

#define NB 16
#define NL 1024
#define NH 8
#define NE 64
#define NWIN 1024
#define NG 64

#define SCH 128     // s-chunk per block in k_attn_out
#define SROW 136    // sb row stride in shorts (16B-aligned: 136*2=272 ≡ 0 mod 16)

typedef __attribute__((ext_vector_type(8))) short short8;
typedef __attribute__((ext_vector_type(4))) float floatx4;

__device__ __forceinline__ short f2bf(float x) {
    unsigned u = __float_as_uint(x);
    u += 0x7fffu + ((u >> 16) & 1u);   // round-to-nearest-even
    return (short)(u >> 16);
}
__device__ __forceinline__ float dot4(float4 a, float4 b) {
    return fmaf(a.x, b.x, fmaf(a.y, b.y, fmaf(a.z, b.z, a.w * b.w)));
}

// Raw barrier: orders LDS traffic (lgkmcnt) but does NOT drain vmcnt —
// keeps the register v-prefetch in flight across phases.
__device__ __forceinline__ void lgkm_barrier() {
    asm volatile("s_waitcnt lgkmcnt(0)" ::: "memory");
    __builtin_amdgcn_s_barrier();
}

// Fused kernel: tanh-MLP (t stays in LDS) + qp/qn reduction.
// v5 (unchanged): one row per 16-lane group, 1024 blocks.
__global__ __launch_bounds__(256, 4) void k_sel_q(
    const float* __restrict__ x, const float* __restrict__ mlp_w,
    const float* __restrict__ mlp_b, const float* __restrict__ q,
    float* __restrict__ qp, float* __restrict__ qn)
{
    __shared__ float4 w_lds[8][NWIN / 4];   // 32 KB
    __shared__ float t_lds[128];
    __shared__ float redp[4][64], redn[4][64];

    int tid = threadIdx.x;
    int blk = blockIdx.x;
    int ee = blk & 7, bh = blk >> 3;
    int b = bh >> 3, h = bh & 7;
    int w = tid >> 6, lane = tid & 63;
    int sq = lane >> 4, c = lane & 15;

    const float4* w4 = (const float4*)mlp_w;
    float4* wl = (float4*)w_lds;
    #pragma unroll
    for (int i = 0; i < 8; ++i)
        wl[tid + 256 * i] = w4[tid + 256 * i];
    __syncthreads();

    // ---- phase 1: tanh-MLP, one row per 16-lane group (16 rows/block) ----
    int row_loc = w * 4 + sq;                               // [0,16)
    int r = b * 1024 + h * 128 + ee * 16 + row_loc;
    const float4* xr = (const float4*)(x + (size_t)r * NWIN);
    float4 a03 = make_float4(0,0,0,0), a47 = make_float4(0,0,0,0);
    #pragma unroll
    for (int i = 0; i < 16; ++i) {
        float4 xv = xr[i * 16 + c];
        a03.x += dot4(xv, w_lds[0][i * 16 + c]);
        a03.y += dot4(xv, w_lds[1][i * 16 + c]);
        a03.z += dot4(xv, w_lds[2][i * 16 + c]);
        a03.w += dot4(xv, w_lds[3][i * 16 + c]);
        a47.x += dot4(xv, w_lds[4][i * 16 + c]);
        a47.y += dot4(xv, w_lds[5][i * 16 + c]);
        a47.z += dot4(xv, w_lds[6][i * 16 + c]);
        a47.w += dot4(xv, w_lds[7][i * 16 + c]);
    }
    // 4-level butterfly within the 16-lane group
    #pragma unroll
    for (int off = 1; off < 16; off <<= 1) {
        a03.x += __shfl_xor(a03.x, off, 64);
        a03.y += __shfl_xor(a03.y, off, 64);
        a03.z += __shfl_xor(a03.z, off, 64);
        a03.w += __shfl_xor(a03.w, off, 64);
        a47.x += __shfl_xor(a47.x, off, 64);
        a47.y += __shfl_xor(a47.y, off, 64);
        a47.z += __shfl_xor(a47.z, off, 64);
        a47.w += __shfl_xor(a47.w, off, 64);
    }
    if (c == 0) {
        float4 b03 = *(const float4*)mlp_b;
        float4 b47 = *(const float4*)(mlp_b + 4);
        float4 t03, t47;
        t03.x = tanhf(a03.x + b03.x); t03.y = tanhf(a03.y + b03.y);
        t03.z = tanhf(a03.z + b03.z); t03.w = tanhf(a03.w + b03.w);
        t47.x = tanhf(a47.x + b47.x); t47.y = tanhf(a47.y + b47.y);
        t47.z = tanhf(a47.z + b47.z); t47.w = tanhf(a47.w + b47.w);
        *(float4*)&t_lds[row_loc * 8]     = t03;
        *(float4*)&t_lds[row_loc * 8 + 4] = t47;
    }
    __syncthreads();

    // ---- phase 2: qp/qn partial over l in [ee*128, ee*128+128) ----
    int lo = sq, e4 = c;
    float4 accp = make_float4(0,0,0,0), accn = make_float4(0,0,0,0);
    #pragma unroll
    for (int i = 0; i < 8; ++i) {
        int l_loc = w * 32 + i * 4 + lo;
        float tv = t_lds[l_loc];
        int l = ee * 128 + l_loc;
        float4 qv = *(const float4*)(q + (((size_t)(b * NL + l)) * NH + h) * NE + e4 * 4);
        float tp = fmaxf(tv, 0.f), tn = fminf(tv, 0.f);
        accp.x = fmaf(tp, qv.x, accp.x); accp.y = fmaf(tp, qv.y, accp.y);
        accp.z = fmaf(tp, qv.z, accp.z); accp.w = fmaf(tp, qv.w, accp.w);
        accn.x = fmaf(tn, qv.x, accn.x); accn.y = fmaf(tn, qv.y, accn.y);
        accn.z = fmaf(tn, qv.z, accn.z); accn.w = fmaf(tn, qv.w, accn.w);
    }
    #pragma unroll
    for (int off = 16; off <= 32; off <<= 1) {
        accp.x += __shfl_xor(accp.x, off, 64); accp.y += __shfl_xor(accp.y, off, 64);
        accp.z += __shfl_xor(accp.z, off, 64); accp.w += __shfl_xor(accp.w, off, 64);
        accn.x += __shfl_xor(accn.x, off, 64); accn.y += __shfl_xor(accn.y, off, 64);
        accn.z += __shfl_xor(accn.z, off, 64); accn.w += __shfl_xor(accn.w, off, 64);
    }
    if (lo == 0) {
        *(float4*)&redp[w][e4 * 4] = accp;
        *(float4*)&redn[w][e4 * 4] = accn;
    }
    __syncthreads();
    if (tid < 64) {
        atomicAdd(&qp[bh * NE + tid], redp[0][tid] + redp[1][tid] + redp[2][tid] + redp[3][tid]);
    } else if (tid < 128) {
        int e = tid - 64;
        atomicAdd(&qn[bh * NE + e], redn[0][e] + redn[1][e] + redn[2][e] + redn[3][e]);
    }
}

// Attention kernel v6: per (b, h, s-chunk of 128).
// v is prefetched into REGISTERS (not LDS): 16 scalar loads at entry
// (ks=0,1, issued AFTER the phase-A k loads — vmcnt retires in order, so
// anything needed earlier must be older), 16 more between phases A and B.
// lgkm-only barriers keep them in flight; phase C's use waits vmcnt.
// LDS back to ~21 KB -> occupancy is VGPR-bound at 4 blocks/CU, grid =
// exactly one full dispatch round (1024 = 256 CU x 4).
__global__ __launch_bounds__(256, 4) void k_attn_out(
    const float* __restrict__ keys, const float* __restrict__ values,
    const float* __restrict__ sel_W,
    const float* __restrict__ qp, const float* __restrict__ qn,
    float* __restrict__ out)
{
    __shared__ short sb[NG][SROW];          // 17408 B  series bf16, [g][s]
    __shared__ float ap_l[SCH], an_l[SCH];  // 1024 B
    __shared__ float2 wpn[NG];              // 512 B
    __shared__ float mx2[2][SCH], dn2[2][SCH];

    int tid = threadIdx.x, blk = blockIdx.x;
    int chunk = blk & 7, bh = blk >> 3;
    int b = bh >> 3, h = bh & 7;
    int w = tid >> 6, lane = tid & 63;
    int c = lane & 15, sq = lane >> 4;
    const float scale = 0.125f;             // 1/sqrt(64)
    int s0 = chunk * SCH;

    // oldest loads first: qp/qn (needed in phase A), wpn (phase B)
    const float4 qp4 = *(const float4*)(qp + bh * NE + c * 4);
    const float4 qn4 = *(const float4*)(qn + bh * NE + c * 4);
    if (tid < NG) {
        float W = sel_W[h * NG + tid];
        wpn[tid] = make_float2(fmaxf(W, 0.f) * scale, fminf(W, 0.f) * scale);
    }

    // phase-A k tile (8 float4 / thread) — issued before the v prefetch
    float4 kvv[8];
    #pragma unroll
    for (int p = 0; p < 8; ++p) {
        int sl = w * 32 + p * 4 + sq;
        kvv[p] = *(const float4*)(keys + (((size_t)(b * NL + s0 + sl)) * NH + h) * NE + c * 4);
    }

    // v prefetch, first half (ks = 0,1): stays in flight through phase A/B
    const float* vbase = values + (((size_t)(b * NL + s0)) * NH + h) * NE + 16 * w + c;
    float vregA[16];
    #pragma unroll
    for (int m = 0; m < 16; ++m)
        vregA[m] = vbase[(size_t)((m >> 3) * 32 + sq * 8 + (m & 7)) * (NH * NE)];
    __builtin_amdgcn_sched_barrier(0);      // pin prefetch issue before phase A

    // ---- phase A: ap/an (wave owns 32 s) ----
    #pragma unroll
    for (int p = 0; p < 8; ++p) {
        int sl = w * 32 + p * 4 + sq;
        float pp = dot4(kvv[p], qp4);
        float pn = dot4(kvv[p], qn4);
        #pragma unroll
        for (int m_ = 1; m_ <= 8; m_ <<= 1) {
            pp += __shfl_xor(pp, m_, 64);
            pn += __shfl_xor(pn, m_, 64);
        }
        if (c == 0) { ap_l[sl] = pp; an_l[sl] = pn; }
    }

    // v prefetch, second half (ks = 2,3): hidden under phase B
    float vregB[16];
    #pragma unroll
    for (int m = 0; m < 16; ++m)
        vregB[m] = vbase[(size_t)((2 + (m >> 3)) * 32 + sq * 8 + (m & 7)) * (NH * NE)];
    __builtin_amdgcn_sched_barrier(0);

    lgkm_barrier();

    // ---- phase B: softmax over g, split g-range across thread halves ----
    {
        int s_ = tid & 127, gh = tid >> 7, g0 = gh * 32;
        float ap = ap_l[s_], an = an_l[s_];
        float m = -1e30f;
        #pragma unroll 8
        for (int g = 0; g < 32; ++g) {
            float2 wv = wpn[g0 + g];
            m = fmaxf(m, fmaf(wv.x, ap, wv.y * an));
        }
        mx2[gh][s_] = m;
        lgkm_barrier();
        m = fmaxf(mx2[0][s_], mx2[1][s_]);
        float d = 0.f;
        #pragma unroll 8
        for (int g = 0; g < 32; ++g) {
            float2 wv = wpn[g0 + g];
            d += __expf(fmaf(wv.x, ap, wv.y * an) - m);
        }
        dn2[gh][s_] = d;
        lgkm_barrier();
        float inv = 1.0f / (dn2[0][s_] + dn2[1][s_]);
        #pragma unroll 8
        for (int g = 0; g < 32; ++g) {
            float2 wv = wpn[g0 + g];
            sb[g0 + g][s_] = f2bf(__expf(fmaf(wv.x, ap, wv.y * an) - m) * inv);
        }
    }
    lgkm_barrier();

    // ---- phase C: MFMA, wave owns e-tile [16w, 16w+16) ----
    // (compiler inserts the vmcnt wait for vregA/vregB first use)
    floatx4 acc[4] = {{0.f,0.f,0.f,0.f},{0.f,0.f,0.f,0.f},
                      {0.f,0.f,0.f,0.f},{0.f,0.f,0.f,0.f}};
    #pragma unroll
    for (int ks = 0; ks < 4; ++ks) {
        short8 av;
        #pragma unroll
        for (int j = 0; j < 8; ++j)
            av[j] = f2bf(ks < 2 ? vregA[ks * 8 + j] : vregB[(ks - 2) * 8 + j]);
        #pragma unroll
        for (int n = 0; n < 4; ++n) {
            short8 bv = *(const short8*)&sb[16 * n + c][ks * 32 + sq * 8];
            acc[n] = __builtin_amdgcn_mfma_f32_16x16x32_bf16(av, bv, acc[n], 0, 0, 0);
        }
    }

    // epilogue: D[row=sq*4+r][col=c]; 8 s-chunk blocks accumulate per (b,h).
    #pragma unroll
    for (int n = 0; n < 4; ++n) {
        #pragma unroll
        for (int r = 0; r < 4; ++r) {
            int e = 16 * w + sq * 4 + r;
            int g = 16 * n + c;
            atomicAdd(&out[((size_t)(b * NE + e) * NH + h) * NG + g], acc[n][r]);
        }
    }
}

extern "C" void kernel_launch(void* const* d_in, const int* in_sizes, int n_in,
                              void* d_out, int out_size, void* d_ws, size_t ws_size,
                              hipStream_t stream) {
    (void)in_sizes; (void)n_in; (void)ws_size;
    const float* queries = (const float*)d_in[0];
    const float* keys    = (const float*)d_in[1];
    const float* values  = (const float*)d_in[2];
    const float* x       = (const float*)d_in[3];
    const float* mlp_w   = (const float*)d_in[4];
    const float* mlp_b   = (const float*)d_in[5];
    const float* sel_W   = (const float*)d_in[6];
    float* out = (float*)d_out;

    // ws layout (floats): qp[8192] | qn[8192]
    float* qp_ws = (float*)d_ws;
    float* qn_ws = qp_ws + NB * NH * NE;

    hipMemsetAsync(out, 0, (size_t)out_size * sizeof(float), stream);
    hipMemsetAsync(qp_ws, 0, (size_t)2 * NB * NH * NE * sizeof(float), stream);

    k_sel_q<<<dim3(NB * NH * 8), dim3(256), 0, stream>>>(x, mlp_w, mlp_b,
                                                          queries, qp_ws, qn_ws);
    k_attn_out<<<dim3(NB * NH * 8), dim3(256), 0, stream>>>(keys, values, sel_W,
                                                            qp_ws, qn_ws, out);
}